// Round 2
// baseline (186.034 us; speedup 1.0000x reference)
//
#include <hip/hip_runtime.h>

#define NGRAPH 1000
#define P      100
#define EPG    1200
#define INF    16
#define HID    64
#define NOUT   5

// r20 = r19 structure (dense-MFMA propagation, verified) + storage rework:
//  - Activations in LDS as PACKED u32 = (bf16hi<<16)|bf16lo (RNE split at
//    write). MFMA fragments built with v_perm_b32 (8 VALU/frag vs 40 bsplit).
//  - Col swizzle col ^= ((row>>3)&3)<<3: prop B-frag reads (rows +8 apart,
//    previously 4-way bank conflict at ASTR=100) become 2-way (free); W-phase
//    b128 A-frag reads stay contiguous+16B-aligned (XOR only touches col bits
//    3..4, fragment base cols are multiples of 8).
//  - Adjacency MFMA A-fragments hoisted to registers ONCE per kernel
//    (short8 a0k[4]/a1k[4], 32 VGPR) — reused by all 18 props.
//  - Pool/FC via wave shuffle-reduce; LDS = 40,000 (Ap) + 512 (meta) B.
// HARD RULES kept: compile-time unrolled acc/frag arrays only; verified MFMA
// lane mappings (A: row=l&15,k=8*(l>>4)+j; B: col=l&15; D: col=l&15,
// row=4*(l>>4)+reg) unchanged from the 186us/82us kernels.

#define ASTR   100
#define T1OFF  64
#define T2OFF  80

#define AINT_K  128
#define AINT_SZ (P * AINT_K)

#define RK1 64
#define RK2 208
#define L1HI 0
#define L1LO 4096
#define L2HI 8192
#define L2LO 21504
#define L3HI 34816
#define L3LO 48128
#define WT_SHORTS 61440

typedef short short8 __attribute__((ext_vector_type(8)));
typedef float f32x4  __attribute__((ext_vector_type(4)));
typedef int   int4v  __attribute__((ext_vector_type(4)));

// swizzled linear index into packed activation LDS
__device__ __forceinline__ int sw(int row, int col) {
    return row * ASTR + (col ^ (((row >> 3) & 3) << 3));
}

// RNE split of fp32 into (bf16hi<<16)|bf16lo
__device__ __forceinline__ unsigned packsplit(float x) {
    unsigned u  = __float_as_uint(x);
    unsigned hi = (u + 0x7fffu + ((u >> 16) & 1u)) >> 16;
    float r = x - __uint_as_float(hi << 16);
    unsigned v  = __float_as_uint(r);
    unsigned lo = (v + 0x7fffu + ((v >> 16) & 1u)) >> 16;
    return (hi << 16) | (lo & 0xffffu);
}

__device__ __forceinline__ float unpack(unsigned p) {
    return __uint_as_float(p & 0xffff0000u) + __uint_as_float(p << 16);
}

// v_perm selectors: first arg = S0 (high dword), second = S1 (low dword);
// sel 0-3 -> S1 bytes, 4-7 -> S0 bytes.
// hi-pair(u_even, u_odd): {hi16(u_even) in low16, hi16(u_odd) in high16}
#define PSEL_HI 0x07060302u
#define PSEL_LO 0x05040100u

__device__ __forceinline__ short8 mk_hi(const unsigned* u) {
    int4v h;
    h[0] = (int)__builtin_amdgcn_perm(u[1], u[0], PSEL_HI);
    h[1] = (int)__builtin_amdgcn_perm(u[3], u[2], PSEL_HI);
    h[2] = (int)__builtin_amdgcn_perm(u[5], u[4], PSEL_HI);
    h[3] = (int)__builtin_amdgcn_perm(u[7], u[6], PSEL_HI);
    return __builtin_bit_cast(short8, h);
}
__device__ __forceinline__ short8 mk_lo(const unsigned* u) {
    int4v h;
    h[0] = (int)__builtin_amdgcn_perm(u[1], u[0], PSEL_LO);
    h[1] = (int)__builtin_amdgcn_perm(u[3], u[2], PSEL_LO);
    h[2] = (int)__builtin_amdgcn_perm(u[5], u[4], PSEL_LO);
    h[3] = (int)__builtin_amdgcn_perm(u[7], u[6], PSEL_LO);
    return __builtin_bit_cast(short8, h);
}

// ---- W split/transpose pre-kernel ----
__global__ __launch_bounds__(256) void wprep(
    const float* __restrict__ W1, const float* __restrict__ W2,
    const float* __restrict__ W3, short* __restrict__ wt)
{
    const int i0 = blockIdx.x * blockDim.x + threadIdx.x;
    const int stride = gridDim.x * blockDim.x;
    for (int e = i0; e < HID * RK1; e += stride) {
        int c = e / RK1, r = e % RK1;
        float v = (r < 3 * INF) ? W1[r * HID + c] : 0.f;
        unsigned p = packsplit(v);
        wt[L1HI + e] = (short)(p >> 16);
        wt[L1LO + e] = (short)(p & 0xffffu);
    }
    for (int e = i0; e < HID * RK2; e += stride) {
        int c = e / RK2, r = e % RK2;
        float v2 = (r < 3 * HID) ? W2[r * HID + c] : 0.f;
        float v3 = (r < 3 * HID) ? W3[r * HID + c] : 0.f;
        unsigned p2 = packsplit(v2), p3 = packsplit(v3);
        wt[L2HI + e] = (short)(p2 >> 16); wt[L2LO + e] = (short)(p2 & 0xffffu);
        wt[L3HI + e] = (short)(p3 >> 16); wt[L3LO + e] = (short)(p3 & 0xffffu);
    }
}

// ---- per-graph dense adjacency build: counts (u16 halves) -> bf16 ----
__global__ __launch_bounds__(256) void abuild(
    const int* __restrict__ src, const int* __restrict__ dst,
    short* __restrict__ aint)
{
    __shared__ unsigned int cnt[AINT_SZ / 2];     // 25,600 B
    const int g = blockIdx.x, tid = threadIdx.x, base = g * P;
    for (int i = tid; i < AINT_SZ / 2; i += 256) cnt[i] = 0u;
    __syncthreads();
    const int* srcg = src + g * EPG;
    const int* dstg = dst + g * EPG;
    for (int e = tid; e < EPG; e += 256) {
        int s = srcg[e] - base;
        int d = dstg[e] - base;
        int idx = d * AINT_K + s;
        atomicAdd(&cnt[idx >> 1], 1u << ((idx & 1) * 16));
    }
    __syncthreads();
    unsigned int* outw = (unsigned int*)(aint + (size_t)g * AINT_SZ);
    for (int i = tid; i < AINT_SZ / 2; i += 256) {
        unsigned int u = cnt[i];
        unsigned int b0 = __float_as_uint((float)(u & 0xffffu)) >> 16;
        unsigned int b1 = __float_as_uint((float)(u >> 16)) >> 16;
        outw[i] = b0 | (b1 << 16);
    }
}

// ---- one dense propagation over packed LDS ----
// SECOND=0: T1 = -d^2 (Aint @ src);  SECOND=1: T2 = -2 d^2 (Aint @ src) - Y
template <int SECOND>
__device__ __forceinline__ void dense_prop(
    unsigned* __restrict__ Ap, const short8* a0k, const short8* a1k, bool has2,
    int srcoff, int dstoff, int ycb,
    int rb0, int rb1, f32x4 dv0, f32x4 dv1, int lane)
{
    const int n16 = lane & 15;
    const int q   = lane >> 4;
    const int kq  = q * 8;
    f32x4 p0, p1;
    p0[0]=0.f; p0[1]=0.f; p0[2]=0.f; p0[3]=0.f;
    p1[0]=0.f; p1[1]=0.f; p1[2]=0.f; p1[3]=0.f;
#pragma unroll
    for (int k = 0; k < 4; k++) {
        unsigned u[8];
#pragma unroll
        for (int j = 0; j < 8; j++) {
            int row = k * 32 + kq + j;
            if (k == 3) row = (row < P) ? row : 0;   // Aint cols >=100 are 0
            u[j] = Ap[sw(row, srcoff + n16)];
        }
        const short8 bhi = mk_hi(u);
        const short8 blo = mk_lo(u);
        p0 = __builtin_amdgcn_mfma_f32_16x16x32_bf16(a0k[k], bhi, p0, 0, 0, 0);
        p0 = __builtin_amdgcn_mfma_f32_16x16x32_bf16(a0k[k], blo, p0, 0, 0, 0);
        if (has2) {
            p1 = __builtin_amdgcn_mfma_f32_16x16x32_bf16(a1k[k], bhi, p1, 0, 0, 0);
            p1 = __builtin_amdgcn_mfma_f32_16x16x32_bf16(a1k[k], blo, p1, 0, 0, 0);
        }
    }
#pragma unroll
    for (int r = 0; r < 4; r++) {
        const int row = rb0 + q * 4 + r;
        const float d2 = dv0[r] * dv0[r];
        float o;
        if (SECOND) o = -2.f * d2 * p0[r] - unpack(Ap[sw(row, ycb + n16)]);
        else        o = -d2 * p0[r];
        Ap[sw(row, dstoff + n16)] = packsplit(o);
    }
    if (has2) {
#pragma unroll
        for (int r = 0; r < 4; r++) {
            const int row = rb1 + q * 4 + r;
            if (rb1 != 84 || row >= 96) {            // tile-6 overlap guard
                const float d2 = dv1[r] * dv1[r];
                float o;
                if (SECOND) o = -2.f * d2 * p1[r] - unpack(Ap[sw(row, ycb + n16)]);
                else        o = -d2 * p1[r];
                Ap[sw(row, dstoff + n16)] = packsplit(o);
            }
        }
    }
}

// ---- one ChebConv layer ----
template <int F, int FINAL>
__device__ __forceinline__ void cheb_layer(
    unsigned* __restrict__ Ap, const float* __restrict__ dinv,
    const short8* a0k, const short8* a1k, bool has2,
    const short* __restrict__ whi, const short* __restrict__ wlo,
    const float* __restrict__ bias,
    int tid, int rb0, int rb1, f32x4 dv0, f32x4 dv1)
{
    const int RK   = 3 * F + 16;
    const int lane = tid & 63;
    const int wv   = tid >> 6;
    const int n16  = lane & 15;
    const int q    = lane >> 4;
    const int ncol = (wv << 4) + n16;

    f32x4 acc[7];
#pragma unroll
    for (int t = 0; t < 7; t++) { acc[t][0]=0.f; acc[t][1]=0.f; acc[t][2]=0.f; acc[t][3]=0.f; }

    for (int cb = 0; cb < F; cb += 16) {
        dense_prop<0>(Ap, a0k, a1k, has2, cb,    T1OFF, 0,  rb0, rb1, dv0, dv1, lane);
        __syncthreads();
        dense_prop<1>(Ap, a0k, a1k, has2, T1OFF, T2OFF, cb, rb0, rb1, dv0, dv1, lane);
        __syncthreads();

        // W partial: chunk K-layout [Y16 | T1_16 | T2_16 | zero16], 2 K-steps
#pragma unroll
        for (int ks = 0; ks < 2; ks++) {
            int wr, aoff;
            if (ks == 0) {
                wr   = (q == 0) ? cb : (q == 1) ? cb + 8 : (q == 2) ? F + cb : F + cb + 8;
                aoff = (q == 0) ? cb : (q == 1) ? cb + 8 : (q == 2) ? T1OFF  : T1OFF + 8;
            } else {
                wr   = (q == 0) ? 2*F + cb : (q == 1) ? 2*F + cb + 8 : (q == 2) ? 3*F : 3*F + 8;
                aoff = (q == 0) ? T2OFF    : (q == 1) ? T2OFF + 8    : (q == 2) ? T1OFF : T1OFF + 8;
            }
            const short8 bhi = *(const short8*)&whi[ncol * RK + wr];
            const short8 blo = *(const short8*)&wlo[ncol * RK + wr];
#pragma unroll
            for (int t = 0; t < 7; t++) {
                const int row = ((t < 6) ? t * 16 : 84) + n16;
                const unsigned* xp = &Ap[sw(row, aoff)];   // XOR keeps 8-block contiguous
                const int4v w0 = *(const int4v*)xp;
                const int4v w1 = *(const int4v*)(xp + 4);
                unsigned u[8];
                u[0]=(unsigned)w0[0]; u[1]=(unsigned)w0[1]; u[2]=(unsigned)w0[2]; u[3]=(unsigned)w0[3];
                u[4]=(unsigned)w1[0]; u[5]=(unsigned)w1[1]; u[6]=(unsigned)w1[2]; u[7]=(unsigned)w1[3];
                const short8 ahi = mk_hi(u);
                const short8 alo = mk_lo(u);
                acc[t] = __builtin_amdgcn_mfma_f32_16x16x32_bf16(ahi, bhi, acc[t], 0, 0, 0);
                acc[t] = __builtin_amdgcn_mfma_f32_16x16x32_bf16(ahi, blo, acc[t], 0, 0, 0);
                acc[t] = __builtin_amdgcn_mfma_f32_16x16x32_bf16(alo, bhi, acc[t], 0, 0, 0);
            }
        }
        __syncthreads();
    }

    // Epilogue (D: col=lane&15, row=4*(lane>>4)+reg; tile 6 -> rows 84..99)
    const float bcol = bias[ncol];
#pragma unroll
    for (int t = 0; t < 7; t++) {
        const int rbase = ((t < 6) ? t * 16 : 84) + q * 4;
#pragma unroll
        for (int r = 0; r < 4; r++) {
            const int row = rbase + r;
            if (t < 6 || row >= 96) {
                const float dn = dinv[row];
                const float v = acc[t][r];
                float o;
                if (FINAL) o = fmaxf(v * (1.0f / dn) + bcol, 0.f);
                else       o = fmaxf(v + bcol * dn, 0.f);
                Ap[sw(row, ncol)] = packsplit(o);
            }
        }
    }
    __syncthreads();
}

__global__ __launch_bounds__(256, 4) void gnn_kernel(
    const float* __restrict__ feat,
    const int* __restrict__ src, const int* __restrict__ dst,
    const float* __restrict__ b1, const float* __restrict__ b2,
    const float* __restrict__ b3,
    const float* __restrict__ Wfc, const float* __restrict__ bfc,
    const short* __restrict__ wt, const short* __restrict__ aint,
    float* __restrict__ out)
{
    __shared__ __align__(16) unsigned Ap[P * ASTR];   // 40,000 B packed hi|lo
    __shared__ float meta[128];                        // dinv[100] + pool[20]

    const int g = blockIdx.x;
    const int tid = threadIdx.x;
    const int base = g * P;
    const int* dstg = dst + g * EPG;

    // ---- degree count (meta as int scratch) ----
    int* deg = (int*)meta;
    for (int i = tid; i < P; i += 256) deg[i] = 0;
    __syncthreads();
    for (int e = tid; e < EPG; e += 256) atomicAdd(&deg[dstg[e] - base], 1);
    __syncthreads();
    for (int i = tid; i < P; i += 256) {
        int dg = deg[i];
        meta[i] = rsqrtf((float)(dg > 1 ? dg : 1));
    }
    __syncthreads();

    // ---- feat load prescaled (Y = dinv*feat), packed ----
    for (int i = tid; i < P * INF / 4; i += 256) {
        int n = i >> 2, f0 = (i & 3) * 4;
        float4 v = *(const float4*)&feat[(size_t)base * INF + i * 4];
        float dn = meta[n];
        int4v pk;
        pk[0] = (int)packsplit(v.x * dn);
        pk[1] = (int)packsplit(v.y * dn);
        pk[2] = (int)packsplit(v.z * dn);
        pk[3] = (int)packsplit(v.w * dn);
        *(int4v*)&Ap[sw(n, f0)] = pk;    // XOR keeps 4-block contiguous+aligned
    }
    __syncthreads();

    // ---- per-wave tile assignment, dinv regs, adjacency regs (per kernel) ----
    const int lane = tid & 63, wv = tid >> 6, q = lane >> 4, n16 = lane & 15;
    const int rb0 = wv * 16;
    const int t2i = wv + 4;
    const int rb1 = (t2i >= 6) ? 84 : t2i * 16;
    const bool has2 = (wv < 3);
    f32x4 dv0, dv1;
#pragma unroll
    for (int r = 0; r < 4; r++) {
        dv0[r] = meta[rb0 + q * 4 + r];
        dv1[r] = meta[(has2 ? rb1 : rb0) + q * 4 + r];
    }
    const short* aintg = aint + (size_t)g * AINT_SZ;
    const int arow0 = rb0 + n16;
    const int arow1 = (has2 ? rb1 : rb0) + n16;
    short8 a0k[4], a1k[4];
#pragma unroll
    for (int k = 0; k < 4; k++) {
        a0k[k] = *(const short8*)&aintg[arow0 * AINT_K + k * 32 + q * 8];
        a1k[k] = *(const short8*)&aintg[arow1 * AINT_K + k * 32 + q * 8];
    }

    cheb_layer<INF, 0>(Ap, meta, a0k, a1k, has2, wt + L1HI, wt + L1LO, b1, tid, rb0, rb1, dv0, dv1);
    cheb_layer<HID, 0>(Ap, meta, a0k, a1k, has2, wt + L2HI, wt + L2LO, b2, tid, rb0, rb1, dv0, dv1);
    cheb_layer<HID, 1>(Ap, meta, a0k, a1k, has2, wt + L3HI, wt + L3LO, b3, tid, rb0, rb1, dv0, dv1);

    // ---- mean pool + FC: per-wave column sums -> per-wave partial FC ->
    //      wave shuffle-reduce -> 4x5 partials in meta -> final combine ----
    {
        const int l = tid & 63, w = tid >> 6;
        float s = 0.f;
        for (int n = w; n < P; n += 4) s += unpack(Ap[sw(n, l)]);
        float o0 = s * Wfc[l * NOUT + 0];
        float o1 = s * Wfc[l * NOUT + 1];
        float o2 = s * Wfc[l * NOUT + 2];
        float o3 = s * Wfc[l * NOUT + 3];
        float o4 = s * Wfc[l * NOUT + 4];
#pragma unroll
        for (int d = 1; d < 64; d <<= 1) {
            o0 += __shfl_xor(o0, d);
            o1 += __shfl_xor(o1, d);
            o2 += __shfl_xor(o2, d);
            o3 += __shfl_xor(o3, d);
            o4 += __shfl_xor(o4, d);
        }
        if (l == 0) {
            meta[100 + w * NOUT + 0] = o0;
            meta[100 + w * NOUT + 1] = o1;
            meta[100 + w * NOUT + 2] = o2;
            meta[100 + w * NOUT + 3] = o3;
            meta[100 + w * NOUT + 4] = o4;
        }
    }
    __syncthreads();
    if (tid < NOUT) {
        float o = meta[100 + tid] + meta[105 + tid] + meta[110 + tid] + meta[115 + tid];
        out[g * NOUT + tid] = bfc[tid] + o * (1.0f / P);
    }
}

extern "C" void kernel_launch(void* const* d_in, const int* in_sizes, int n_in,
                              void* d_out, int out_size, void* d_ws, size_t ws_size,
                              hipStream_t stream)
{
    const float* feat = (const float*)d_in[0];
    const int*   src  = (const int*)d_in[1];
    const int*   dst  = (const int*)d_in[2];
    const float* W1  = (const float*)d_in[5];
    const float* b1  = (const float*)d_in[6];
    const float* W2  = (const float*)d_in[7];
    const float* b2  = (const float*)d_in[8];
    const float* W3  = (const float*)d_in[9];
    const float* b3  = (const float*)d_in[10];
    const float* Wfc = (const float*)d_in[11];
    const float* bfc = (const float*)d_in[12];
    float* out = (float*)d_out;

    short* wt   = (short*)d_ws;                 // 122,880 B
    short* aint = wt + WT_SHORTS;               // + 25,600,000 B

    wprep<<<64, 256, 0, stream>>>(W1, W2, W3, wt);
    abuild<<<NGRAPH, 256, 0, stream>>>(src, dst, aint);
    gnn_kernel<<<NGRAPH, 256, 0, stream>>>(feat, src, dst,
                                           b1, b2, b3, Wfc, bfc, wt, aint, out);
}

// Round 5
// 180.844 us; speedup vs baseline: 1.0287x; 1.0287x over previous
//
#include <hip/hip_runtime.h>

#define NGRAPH 1000
#define P      100
#define EPG    1200
#define INF    16
#define HID    64
#define NOUT   5

// r23 = r21 resubmitted a 2nd time (two infra "container failed twice" rounds;
// kernel audited: no divergent barriers, all LDS indices bounded, numerics
// identical to the PASSING r20, only the rule-#20 scratch leak removed).
// r21 = r20 design (packed hi|lo activations + perm fragment builds + col-XOR
// swizzle + dense-MFMA props) with the SCRATCH LEAK fixed:
//  - r20 regression root cause (rocprof): WRITE_SIZE 47KB -> 42MB = local-mem
//    spill. `unsigned u[8]` + `short8 a0k[4]` passed BY POINTER defeated SROA
//    (guide rule #20). All local arrays/pointers-to-locals are eliminated:
//    adjacency fragments passed by value (8 named short8), fragment builds use
//    named scalars + constant-index ext_vector writes only.
//  - Packed u32 = (bf16hi<<16)|bf16lo activations, RNE split at write time;
//    MFMA fragments via v_perm_b32 pairs (8 VALU/frag vs 40 bsplit).
//  - sw(): col ^= ((row>>3)&3)<<3 — prop B-frag reads conflict-free (quads
//    spread across all 32 banks); W-phase b128 reads stay contiguous+aligned.
//  - LDS: Ap 40,000 B + meta 512 B -> 4 blocks/CU.
// HARD RULES: no runtime-indexed local arrays (acc[7]/unrolled loops only —
// proven clean in r19); verified MFMA lane mappings unchanged.

#define ASTR   100
#define T1OFF  64
#define T2OFF  80

#define AINT_K  128
#define AINT_SZ (P * AINT_K)

#define RK1 64
#define RK2 208
#define L1HI 0
#define L1LO 4096
#define L2HI 8192
#define L2LO 21504
#define L3HI 34816
#define L3LO 48128
#define WT_SHORTS 61440

typedef short short8 __attribute__((ext_vector_type(8)));
typedef float f32x4  __attribute__((ext_vector_type(4)));
typedef int   int4v  __attribute__((ext_vector_type(4)));

// swizzled linear index into packed activation LDS
__device__ __forceinline__ int sw(int row, int col) {
    return row * ASTR + (col ^ (((row >> 3) & 3) << 3));
}

// RNE split of fp32 into (bf16hi<<16)|bf16lo
__device__ __forceinline__ unsigned packsplit(float x) {
    unsigned u  = __float_as_uint(x);
    unsigned hi = (u + 0x7fffu + ((u >> 16) & 1u)) >> 16;
    float r = x - __uint_as_float(hi << 16);
    unsigned v  = __float_as_uint(r);
    unsigned lo = (v + 0x7fffu + ((v >> 16) & 1u)) >> 16;
    return (hi << 16) | (lo & 0xffffu);
}

__device__ __forceinline__ float unpack(unsigned p) {
    return __uint_as_float(p & 0xffff0000u) + __uint_as_float(p << 16);
}

// v_perm selectors: sel bytes 0-3 pick from S1 (2nd arg), 4-7 from S0 (1st).
// HI: result = (hi16(S0)<<16)|hi16(S1);  LO: (lo16(S0)<<16)|lo16(S1)
#define PSEL_HI 0x07060302u
#define PSEL_LO 0x05040100u

// ---- W split/transpose pre-kernel ----
__global__ __launch_bounds__(256) void wprep(
    const float* __restrict__ W1, const float* __restrict__ W2,
    const float* __restrict__ W3, short* __restrict__ wt)
{
    const int i0 = blockIdx.x * blockDim.x + threadIdx.x;
    const int stride = gridDim.x * blockDim.x;
    for (int e = i0; e < HID * RK1; e += stride) {
        int c = e / RK1, r = e % RK1;
        float v = (r < 3 * INF) ? W1[r * HID + c] : 0.f;
        unsigned p = packsplit(v);
        wt[L1HI + e] = (short)(p >> 16);
        wt[L1LO + e] = (short)(p & 0xffffu);
    }
    for (int e = i0; e < HID * RK2; e += stride) {
        int c = e / RK2, r = e % RK2;
        float v2 = (r < 3 * HID) ? W2[r * HID + c] : 0.f;
        float v3 = (r < 3 * HID) ? W3[r * HID + c] : 0.f;
        unsigned p2 = packsplit(v2), p3 = packsplit(v3);
        wt[L2HI + e] = (short)(p2 >> 16); wt[L2LO + e] = (short)(p2 & 0xffffu);
        wt[L3HI + e] = (short)(p3 >> 16); wt[L3LO + e] = (short)(p3 & 0xffffu);
    }
}

// ---- per-graph dense adjacency build: counts (u16 halves) -> bf16 ----
__global__ __launch_bounds__(256) void abuild(
    const int* __restrict__ src, const int* __restrict__ dst,
    short* __restrict__ aint)
{
    __shared__ unsigned int cnt[AINT_SZ / 2];     // 25,600 B
    const int g = blockIdx.x, tid = threadIdx.x, base = g * P;
    for (int i = tid; i < AINT_SZ / 2; i += 256) cnt[i] = 0u;
    __syncthreads();
    const int* srcg = src + g * EPG;
    const int* dstg = dst + g * EPG;
    for (int e = tid; e < EPG; e += 256) {
        int s = srcg[e] - base;
        int d = dstg[e] - base;
        int idx = d * AINT_K + s;
        atomicAdd(&cnt[idx >> 1], 1u << ((idx & 1) * 16));
    }
    __syncthreads();
    unsigned int* outw = (unsigned int*)(aint + (size_t)g * AINT_SZ);
    for (int i = tid; i < AINT_SZ / 2; i += 256) {
        unsigned int u = cnt[i];
        unsigned int b0 = __float_as_uint((float)(u & 0xffffu)) >> 16;
        unsigned int b1 = __float_as_uint((float)(u >> 16)) >> 16;
        outw[i] = b0 | (b1 << 16);
    }
}

// ---- one dense propagation over packed LDS (all-register fragments) ----
// SECOND=0: T1 = -d^2 (Aint @ src);  SECOND=1: T2 = -2 d^2 (Aint @ src) - Y
template <int SECOND>
__device__ __forceinline__ void dense_prop(
    unsigned* __restrict__ Ap,
    short8 a00, short8 a01, short8 a02, short8 a03,
    short8 a10, short8 a11, short8 a12, short8 a13,
    bool has2, int srcoff, int dstoff, int ycb,
    int rb0, int rb1, f32x4 dv0, f32x4 dv1, int lane)
{
    const int n16 = lane & 15;
    const int q   = lane >> 4;
    const int kq  = q * 8;
    const int c   = srcoff + n16;
    f32x4 p0, p1;
    p0[0]=0.f; p0[1]=0.f; p0[2]=0.f; p0[3]=0.f;
    p1[0]=0.f; p1[1]=0.f; p1[2]=0.f; p1[3]=0.f;

#define PROPK(KK, A0, A1) { \
    const int rr = KK * 32 + kq; \
    const unsigned u0 = Ap[sw((KK < 3 || rr + 0 < P) ? rr + 0 : 0, c)]; \
    const unsigned u1 = Ap[sw((KK < 3 || rr + 1 < P) ? rr + 1 : 0, c)]; \
    const unsigned u2 = Ap[sw((KK < 3 || rr + 2 < P) ? rr + 2 : 0, c)]; \
    const unsigned u3 = Ap[sw((KK < 3 || rr + 3 < P) ? rr + 3 : 0, c)]; \
    const unsigned u4 = Ap[sw((KK < 3 || rr + 4 < P) ? rr + 4 : 0, c)]; \
    const unsigned u5 = Ap[sw((KK < 3 || rr + 5 < P) ? rr + 5 : 0, c)]; \
    const unsigned u6 = Ap[sw((KK < 3 || rr + 6 < P) ? rr + 6 : 0, c)]; \
    const unsigned u7 = Ap[sw((KK < 3 || rr + 7 < P) ? rr + 7 : 0, c)]; \
    int4v hh, ll; \
    hh[0] = (int)__builtin_amdgcn_perm(u1, u0, PSEL_HI); \
    hh[1] = (int)__builtin_amdgcn_perm(u3, u2, PSEL_HI); \
    hh[2] = (int)__builtin_amdgcn_perm(u5, u4, PSEL_HI); \
    hh[3] = (int)__builtin_amdgcn_perm(u7, u6, PSEL_HI); \
    ll[0] = (int)__builtin_amdgcn_perm(u1, u0, PSEL_LO); \
    ll[1] = (int)__builtin_amdgcn_perm(u3, u2, PSEL_LO); \
    ll[2] = (int)__builtin_amdgcn_perm(u5, u4, PSEL_LO); \
    ll[3] = (int)__builtin_amdgcn_perm(u7, u6, PSEL_LO); \
    const short8 bhi = __builtin_bit_cast(short8, hh); \
    const short8 blo = __builtin_bit_cast(short8, ll); \
    p0 = __builtin_amdgcn_mfma_f32_16x16x32_bf16(A0, bhi, p0, 0, 0, 0); \
    p0 = __builtin_amdgcn_mfma_f32_16x16x32_bf16(A0, blo, p0, 0, 0, 0); \
    if (has2) { \
        p1 = __builtin_amdgcn_mfma_f32_16x16x32_bf16(A1, bhi, p1, 0, 0, 0); \
        p1 = __builtin_amdgcn_mfma_f32_16x16x32_bf16(A1, blo, p1, 0, 0, 0); \
    } }

    PROPK(0, a00, a10)
    PROPK(1, a01, a11)
    PROPK(2, a02, a12)
    PROPK(3, a03, a13)
#undef PROPK

#pragma unroll
    for (int r = 0; r < 4; r++) {
        const int row = rb0 + q * 4 + r;
        const float d2 = dv0[r] * dv0[r];
        float o;
        if (SECOND) o = -2.f * d2 * p0[r] - unpack(Ap[sw(row, ycb + n16)]);
        else        o = -d2 * p0[r];
        Ap[sw(row, dstoff + n16)] = packsplit(o);
    }
    if (has2) {
#pragma unroll
        for (int r = 0; r < 4; r++) {
            const int row = rb1 + q * 4 + r;
            if (rb1 != 84 || row >= 96) {            // tile-6 overlap guard
                const float d2 = dv1[r] * dv1[r];
                float o;
                if (SECOND) o = -2.f * d2 * p1[r] - unpack(Ap[sw(row, ycb + n16)]);
                else        o = -d2 * p1[r];
                Ap[sw(row, dstoff + n16)] = packsplit(o);
            }
        }
    }
}

// ---- one ChebConv layer ----
template <int F, int FINAL>
__device__ __forceinline__ void cheb_layer(
    unsigned* __restrict__ Ap, const float* __restrict__ dinv,
    short8 a00, short8 a01, short8 a02, short8 a03,
    short8 a10, short8 a11, short8 a12, short8 a13, bool has2,
    const short* __restrict__ whi, const short* __restrict__ wlo,
    const float* __restrict__ bias,
    int tid, int rb0, int rb1, f32x4 dv0, f32x4 dv1)
{
    const int RK   = 3 * F + 16;
    const int lane = tid & 63;
    const int wv   = tid >> 6;
    const int n16  = lane & 15;
    const int q    = lane >> 4;
    const int ncol = (wv << 4) + n16;

    f32x4 acc[7];
#pragma unroll
    for (int t = 0; t < 7; t++) { acc[t][0]=0.f; acc[t][1]=0.f; acc[t][2]=0.f; acc[t][3]=0.f; }

    for (int cb = 0; cb < F; cb += 16) {
        dense_prop<0>(Ap, a00,a01,a02,a03, a10,a11,a12,a13, has2,
                      cb,    T1OFF, 0,  rb0, rb1, dv0, dv1, lane);
        __syncthreads();
        dense_prop<1>(Ap, a00,a01,a02,a03, a10,a11,a12,a13, has2,
                      T1OFF, T2OFF, cb, rb0, rb1, dv0, dv1, lane);
        __syncthreads();

        // W partial: chunk K-layout [Y16 | T1_16 | T2_16 | zero16], 2 K-steps
#pragma unroll
        for (int ks = 0; ks < 2; ks++) {
            int wr, aoff;
            if (ks == 0) {
                wr   = (q == 0) ? cb : (q == 1) ? cb + 8 : (q == 2) ? F + cb : F + cb + 8;
                aoff = (q == 0) ? cb : (q == 1) ? cb + 8 : (q == 2) ? T1OFF  : T1OFF + 8;
            } else {
                wr   = (q == 0) ? 2*F + cb : (q == 1) ? 2*F + cb + 8 : (q == 2) ? 3*F : 3*F + 8;
                aoff = (q == 0) ? T2OFF    : (q == 1) ? T2OFF + 8    : (q == 2) ? T1OFF : T1OFF + 8;
            }
            const short8 bhi = *(const short8*)&whi[ncol * RK + wr];
            const short8 blo = *(const short8*)&wlo[ncol * RK + wr];
#pragma unroll
            for (int t = 0; t < 7; t++) {
                const int row = ((t < 6) ? t * 16 : 84) + n16;
                const unsigned* xp = &Ap[sw(row, aoff)];   // XOR keeps 8-block contiguous
                const int4v w0 = *(const int4v*)xp;
                const int4v w1 = *(const int4v*)(xp + 4);
                int4v hh, ll;
                hh[0] = (int)__builtin_amdgcn_perm((unsigned)w0[1], (unsigned)w0[0], PSEL_HI);
                hh[1] = (int)__builtin_amdgcn_perm((unsigned)w0[3], (unsigned)w0[2], PSEL_HI);
                hh[2] = (int)__builtin_amdgcn_perm((unsigned)w1[1], (unsigned)w1[0], PSEL_HI);
                hh[3] = (int)__builtin_amdgcn_perm((unsigned)w1[3], (unsigned)w1[2], PSEL_HI);
                ll[0] = (int)__builtin_amdgcn_perm((unsigned)w0[1], (unsigned)w0[0], PSEL_LO);
                ll[1] = (int)__builtin_amdgcn_perm((unsigned)w0[3], (unsigned)w0[2], PSEL_LO);
                ll[2] = (int)__builtin_amdgcn_perm((unsigned)w1[1], (unsigned)w1[0], PSEL_LO);
                ll[3] = (int)__builtin_amdgcn_perm((unsigned)w1[3], (unsigned)w1[2], PSEL_LO);
                const short8 ahi = __builtin_bit_cast(short8, hh);
                const short8 alo = __builtin_bit_cast(short8, ll);
                acc[t] = __builtin_amdgcn_mfma_f32_16x16x32_bf16(ahi, bhi, acc[t], 0, 0, 0);
                acc[t] = __builtin_amdgcn_mfma_f32_16x16x32_bf16(ahi, blo, acc[t], 0, 0, 0);
                acc[t] = __builtin_amdgcn_mfma_f32_16x16x32_bf16(alo, bhi, acc[t], 0, 0, 0);
            }
        }
        __syncthreads();
    }

    // Epilogue (D: col=lane&15, row=4*(lane>>4)+reg; tile 6 -> rows 84..99)
    const float bcol = bias[ncol];
#pragma unroll
    for (int t = 0; t < 7; t++) {
        const int rbase = ((t < 6) ? t * 16 : 84) + q * 4;
#pragma unroll
        for (int r = 0; r < 4; r++) {
            const int row = rbase + r;
            if (t < 6 || row >= 96) {
                const float dn = dinv[row];
                const float v = acc[t][r];
                float o;
                if (FINAL) o = fmaxf(v * (1.0f / dn) + bcol, 0.f);
                else       o = fmaxf(v + bcol * dn, 0.f);
                Ap[sw(row, ncol)] = packsplit(o);
            }
        }
    }
    __syncthreads();
}

__global__ __launch_bounds__(256, 4) void gnn_kernel(
    const float* __restrict__ feat,
    const int* __restrict__ src, const int* __restrict__ dst,
    const float* __restrict__ b1, const float* __restrict__ b2,
    const float* __restrict__ b3,
    const float* __restrict__ Wfc, const float* __restrict__ bfc,
    const short* __restrict__ wt, const short* __restrict__ aint,
    float* __restrict__ out)
{
    __shared__ __align__(16) unsigned Ap[P * ASTR];   // 40,000 B packed hi|lo
    __shared__ float meta[128];                        // dinv[100] + pool[20]

    const int g = blockIdx.x;
    const int tid = threadIdx.x;
    const int base = g * P;
    const int* dstg = dst + g * EPG;

    // ---- degree count (meta as int scratch) ----
    int* deg = (int*)meta;
    for (int i = tid; i < P; i += 256) deg[i] = 0;
    __syncthreads();
    for (int e = tid; e < EPG; e += 256) atomicAdd(&deg[dstg[e] - base], 1);
    __syncthreads();
    for (int i = tid; i < P; i += 256) {
        int dg = deg[i];
        meta[i] = rsqrtf((float)(dg > 1 ? dg : 1));
    }
    __syncthreads();

    // ---- feat load prescaled (Y = dinv*feat), packed ----
    for (int i = tid; i < P * INF / 4; i += 256) {
        int n = i >> 2, f0 = (i & 3) * 4;
        float4 v = *(const float4*)&feat[(size_t)base * INF + i * 4];
        float dn = meta[n];
        int4v pk;
        pk[0] = (int)packsplit(v.x * dn);
        pk[1] = (int)packsplit(v.y * dn);
        pk[2] = (int)packsplit(v.z * dn);
        pk[3] = (int)packsplit(v.w * dn);
        *(int4v*)&Ap[sw(n, f0)] = pk;    // XOR keeps 4-block contiguous+aligned
    }
    __syncthreads();

    // ---- per-wave tile assignment, dinv regs, adjacency regs (per kernel) ----
    const int lane = tid & 63, wv = tid >> 6, q = lane >> 4, n16 = lane & 15;
    const int rb0 = wv * 16;
    const int t2i = wv + 4;
    const int rb1 = (t2i >= 6) ? 84 : t2i * 16;
    const bool has2 = (wv < 3);
    f32x4 dv0, dv1;
#pragma unroll
    for (int r = 0; r < 4; r++) {
        dv0[r] = meta[rb0 + q * 4 + r];
        dv1[r] = meta[(has2 ? rb1 : rb0) + q * 4 + r];
    }
    const short* aintg = aint + (size_t)g * AINT_SZ;
    const int arow0 = rb0 + n16;
    const int arow1 = (has2 ? rb1 : rb0) + n16;
    const short8 a00 = *(const short8*)&aintg[arow0 * AINT_K +  0 + q * 8];
    const short8 a01 = *(const short8*)&aintg[arow0 * AINT_K + 32 + q * 8];
    const short8 a02 = *(const short8*)&aintg[arow0 * AINT_K + 64 + q * 8];
    const short8 a03 = *(const short8*)&aintg[arow0 * AINT_K + 96 + q * 8];
    const short8 a10 = *(const short8*)&aintg[arow1 * AINT_K +  0 + q * 8];
    const short8 a11 = *(const short8*)&aintg[arow1 * AINT_K + 32 + q * 8];
    const short8 a12 = *(const short8*)&aintg[arow1 * AINT_K + 64 + q * 8];
    const short8 a13 = *(const short8*)&aintg[arow1 * AINT_K + 96 + q * 8];

    cheb_layer<INF, 0>(Ap, meta, a00,a01,a02,a03, a10,a11,a12,a13, has2,
                       wt + L1HI, wt + L1LO, b1, tid, rb0, rb1, dv0, dv1);
    cheb_layer<HID, 0>(Ap, meta, a00,a01,a02,a03, a10,a11,a12,a13, has2,
                       wt + L2HI, wt + L2LO, b2, tid, rb0, rb1, dv0, dv1);
    cheb_layer<HID, 1>(Ap, meta, a00,a01,a02,a03, a10,a11,a12,a13, has2,
                       wt + L3HI, wt + L3LO, b3, tid, rb0, rb1, dv0, dv1);

    // ---- mean pool + FC: per-wave column sums -> partial FC -> shuffle ----
    {
        const int l = tid & 63, w = tid >> 6;
        float s = 0.f;
        for (int n = w; n < P; n += 4) s += unpack(Ap[sw(n, l)]);
        float o0 = s * Wfc[l * NOUT + 0];
        float o1 = s * Wfc[l * NOUT + 1];
        float o2 = s * Wfc[l * NOUT + 2];
        float o3 = s * Wfc[l * NOUT + 3];
        float o4 = s * Wfc[l * NOUT + 4];
#pragma unroll
        for (int d = 1; d < 64; d <<= 1) {
            o0 += __shfl_xor(o0, d);
            o1 += __shfl_xor(o1, d);
            o2 += __shfl_xor(o2, d);
            o3 += __shfl_xor(o3, d);
            o4 += __shfl_xor(o4, d);
        }
        if (l == 0) {
            meta[100 + w * NOUT + 0] = o0;
            meta[100 + w * NOUT + 1] = o1;
            meta[100 + w * NOUT + 2] = o2;
            meta[100 + w * NOUT + 3] = o3;
            meta[100 + w * NOUT + 4] = o4;
        }
    }
    __syncthreads();
    if (tid < NOUT) {
        float o = meta[100 + tid] + meta[105 + tid] + meta[110 + tid] + meta[115 + tid];
        out[g * NOUT + tid] = bfc[tid] + o * (1.0f / P);
    }
}

extern "C" void kernel_launch(void* const* d_in, const int* in_sizes, int n_in,
                              void* d_out, int out_size, void* d_ws, size_t ws_size,
                              hipStream_t stream)
{
    const float* feat = (const float*)d_in[0];
    const int*   src  = (const int*)d_in[1];
    const int*   dst  = (const int*)d_in[2];
    const float* W1  = (const float*)d_in[5];
    const float* b1  = (const float*)d_in[6];
    const float* W2  = (const float*)d_in[7];
    const float* b2  = (const float*)d_in[8];
    const float* W3  = (const float*)d_in[9];
    const float* b3  = (const float*)d_in[10];
    const float* Wfc = (const float*)d_in[11];
    const float* bfc = (const float*)d_in[12];
    float* out = (float*)d_out;

    short* wt   = (short*)d_ws;                 // 122,880 B
    short* aint = wt + WT_SHORTS;               // + 25,600,000 B

    wprep<<<64, 256, 0, stream>>>(W1, W2, W3, wt);
    abuild<<<NGRAPH, 256, 0, stream>>>(src, dst, aint);
    gnn_kernel<<<NGRAPH, 256, 0, stream>>>(feat, src, dst,
                                           b1, b2, b3, Wfc, bfc, wt, aint, out);
}